// Round 10
// baseline (261.518 us; speedup 1.0000x reference)
//
#include <hip/hip_runtime.h>

#define BB 8
#define CC 128
#define HH 64
#define WW 64
#define OO 128
#define KT 9
#define HWs (HH * WW)

typedef __attribute__((ext_vector_type(8))) _Float16 half8;
typedef __attribute__((ext_vector_type(8))) short short8;
typedef __attribute__((ext_vector_type(4))) float f32x4;

__device__ inline unsigned short f2bf(float f) {
    union { float f; unsigned int u; } x; x.f = f;
    unsigned int u = x.u;
    unsigned int r = u + 0x7fff + ((u >> 16) & 1);
    return (unsigned short)(r >> 16);
}

// ---- prep 1: NCHW f32 -> NHWC f16 (proven) ----
__global__ __launch_bounds__(256) void prep_input(
    const float* __restrict__ in, _Float16* __restrict__ out) {
    __shared__ float t[CC][33];
    int b = blockIdx.y;
    int s0 = blockIdx.x * 32;
    int s = threadIdx.x & 31;
    int c0 = threadIdx.x >> 5;
    const float* ip = in + (size_t)b * CC * HWs;
#pragma unroll
    for (int c = 0; c < CC; c += 8)
        t[c + c0][s] = ip[(size_t)(c + c0) * HWs + s0 + s];
    __syncthreads();
    int ws = threadIdx.x >> 3;
    int cg = (threadIdx.x & 7) * 16;
    _Float16 v[16];
#pragma unroll
    for (int i = 0; i < 16; ++i) v[i] = (_Float16)t[cg + i][ws];
    _Float16* op = out + ((size_t)(b * HWs) + s0 + ws) * CC + cg;
    *(half8*)op = *(half8*)&v[0];
    *(half8*)(op + 8) = *(half8*)&v[8];
}

// ---- prep 2 (proven): weight (O,C,3,3) f32 -> wbf[k][o][c] bf16 ----
__global__ __launch_bounds__(256) void prep_weight(
    const float* __restrict__ w, unsigned short* __restrict__ wbf) {
    int i = blockIdx.x * 256 + threadIdx.x;
    if (i >= KT * OO * CC) return;
    int k = i / (OO * CC);
    int r = i % (OO * CC);
    int o = r >> 7, c = r & 127;
    wbf[i] = f2bf(w[o * (CC * KT) + c * KT + k]);
}

// ---- main ----
struct GatherR {
    half8 g[8];                 // [corner][cc]: 4 corners x 2 chunks of 8 ch
    float w00, w01, w10, w11;
};

__device__ __forceinline__ void sample_issue(
    const _Float16* __restrict__ base, int ho, int wo, int cs, int k,
    float oy, float ox, float mm, GatherR& G) {
    int kh = k / 3, kw = k % 3;
    float py = (float)(ho - 1 + kh) + oy;
    float px = (float)(wo - 1 + kw) + ox;
    float fy = floorf(py), fx = floorf(px);
    float wy1 = py - fy, wx1 = px - fx;
    float wy0 = 1.f - wy1, wx0 = 1.f - wx1;
    int y0 = (int)fy, x0 = (int)fx;
    int y1 = y0 + 1, x1 = x0 + 1;
    bool vy0 = (y0 >= 0) & (y0 < HH);
    bool vy1 = (y1 >= 0) & (y1 < HH);
    bool vx0 = (x0 >= 0) & (x0 < WW);
    bool vx1 = (x1 >= 0) & (x1 < WW);
    G.w00 = (vy0 & vx0) ? wy0 * wx0 * mm : 0.f;
    G.w01 = (vy0 & vx1) ? wy0 * wx1 * mm : 0.f;
    G.w10 = (vy1 & vx0) ? wy1 * wx0 * mm : 0.f;
    G.w11 = (vy1 & vx1) ? wy1 * wx1 * mm : 0.f;
    int y0c = min(max(y0, 0), HH - 1), y1c = min(max(y1, 0), HH - 1);
    int x0c = min(max(x0, 0), WW - 1), x1c = min(max(x1, 0), WW - 1);
    const _Float16* p00 = base + (size_t)(y0c * WW + x0c) * CC + cs;
    const _Float16* p01 = base + (size_t)(y0c * WW + x1c) * CC + cs;
    const _Float16* p10 = base + (size_t)(y1c * WW + x0c) * CC + cs;
    const _Float16* p11 = base + (size_t)(y1c * WW + x1c) * CC + cs;
    G.g[0] = *(const half8*)p00;  G.g[1] = *(const half8*)(p00 + 32);
    G.g[2] = *(const half8*)p01;  G.g[3] = *(const half8*)(p01 + 32);
    G.g[4] = *(const half8*)p10;  G.g[5] = *(const half8*)(p10 + 32);
    G.g[6] = *(const half8*)p11;  G.g[7] = *(const half8*)(p11 + 32);
}

__global__ __launch_bounds__(512, 8) void deform_main(
    const _Float16* __restrict__ inh, const unsigned short* __restrict__ wbf,
    const float* __restrict__ offset, const float* __restrict__ mask,
    const float* __restrict__ bias, float* __restrict__ out) {
    // 32 KB: B tile for current tap; reused as f32 reduction buffer at the end
    __shared__ unsigned short Bl[OO * CC];

    // 512 blocks; XCD x owns batch image b = x (2 MB f16 in its 4 MB L2)
    int hw = blockIdx.x;
    int lb = (hw & 7) * 64 + (hw >> 3);
    int ho = lb & 63;
    int b = lb >> 6;

    int tid = threadIdx.x;
    int wv = tid >> 6, l = tid & 63;
    int lr = l & 15, lg = l >> 4;
    int p = wv >> 1;               // pixel quarter (0..3)
    int khalf = wv & 1;            // channel half (0..1)
    int wo = p * 16 + lr;          // this lane's pixel
    int cs = khalf * 64 + lg * 8;  // first channel chunk (second is +32)

    // B staging role: each thread 64 B of one row
    int o_s = tid >> 2;
    int cbyte = (tid & 3) * 64;

    const _Float16* base = inh + (size_t)b * HWs * CC;
    const float* offp = offset + (size_t)b * 18 * HWs + ho * WW + wo;
    const float* mskp = mask + (size_t)b * 9 * HWs + ho * WW + wo;

    f32x4 acc[8] = {};
    GatherR G;
    int4 breg[4];

    // ---- prologue: issue B(0) (oldest vmem), gathers(0), offs(1) ----
    {
        const int4* src = (const int4*)((const char*)wbf + (size_t)o_s * 256 + cbyte);
#pragma unroll
        for (int j = 0; j < 4; ++j) breg[j] = src[j];
        float oy = offp[0], ox = offp[HWs], mm = mskp[0];
        sample_issue(base, ho, wo, cs, 0, oy, ox, mm, G);
    }
    float oyN = offp[2 * HWs], oxN = offp[3 * HWs], mmN = mskp[HWs];

    for (int k = 0; k < KT; ++k) {
        // bar A: previous tap's MFMA reads of Bl are complete on all waves
        __syncthreads();
        // write B(k) (waits only the B(k) loads — older than in-flight gathers)
        {
            char* dst = (char*)Bl + o_s * 256;
#pragma unroll
            for (int j = 0; j < 4; ++j)
                *(int4*)(dst + ((cbyte + j * 16) ^ ((o_s & 15) << 4))) = breg[j];
        }
        // bar B: B(k) visible to all waves
        __syncthreads();

        // issue B(k+1) loads (stay older than gathers(k+1) in the queue)
        if (k < KT - 1) {
            const int4* src = (const int4*)((const char*)wbf +
                              (size_t)(k + 1) * OO * CC * 2 + (size_t)o_s * 256 + cbyte);
#pragma unroll
            for (int j = 0; j < 4; ++j) breg[j] = src[j];
        }

        // interp tap k (waits gathers(k); B(k+1) may stay outstanding)
        short8 af[2];
#pragma unroll
        for (int cc = 0; cc < 2; ++cc)
#pragma unroll
            for (int j = 0; j < 8; ++j) {
                float s = G.w00 * (float)G.g[0 * 2 + cc][j] +
                          G.w01 * (float)G.g[1 * 2 + cc][j] +
                          G.w10 * (float)G.g[2 * 2 + cc][j] +
                          G.w11 * (float)G.g[3 * 2 + cc][j];
                af[cc][j] = (short)f2bf(s);
            }

        // issue gathers(k+1); prefetch offsets(k+2)
        if (k < KT - 1) {
            sample_issue(base, ho, wo, cs, k + 1, oyN, oxN, mmN, G);
            if (k < KT - 2) {
                oyN = offp[(2 * k + 4) * HWs];
                oxN = offp[(2 * k + 5) * HWs];
                mmN = mskp[(k + 2) * HWs];
            }
        }

        // MFMA tap k: A regs, B from Bl (proven swizzle)
#pragma unroll
        for (int cc = 0; cc < 2; ++cc) {
            unsigned colb = (unsigned)((khalf * 2 + cc) * 64 + lg * 16);
#pragma unroll
            for (int n = 0; n < 8; ++n) {
                int o = n * 16 + lr;
                unsigned baddr = (unsigned)(o * 256 + (colb ^ (lr << 4)));
                short8 bf = *(const short8*)((const char*)Bl + baddr);
                acc[n] = __builtin_amdgcn_mfma_f32_16x16x32_bf16(
                    af[cc], bf, acc[n], 0, 0, 0);
            }
        }
    }

    // ---- K-split pair reduction reusing Bl as f32 buffer ----
    __syncthreads();  // all MFMA reads of Bl done before type-punned overwrite
    float* L = (float*)Bl;  // 4 quarters x 16 px x 128 o x 4 B = 32 KB
    if (khalf) {
#pragma unroll
        for (int n = 0; n < 8; ++n)
#pragma unroll
            for (int j = 0; j < 4; ++j)
                L[(size_t)(p * 16 + lg * 4 + j) * 128 + n * 16 + lr] = acc[n][j];
    }
    __syncthreads();
    if (!khalf) {
#pragma unroll
        for (int n = 0; n < 8; ++n) {
            int o = n * 16 + lr;
            float bs = bias[o];
            float4 v;
            v.x = acc[n][0] + bs + L[(size_t)(p * 16 + lg * 4 + 0) * 128 + o];
            v.y = acc[n][1] + bs + L[(size_t)(p * 16 + lg * 4 + 1) * 128 + o];
            v.z = acc[n][2] + bs + L[(size_t)(p * 16 + lg * 4 + 2) * 128 + o];
            v.w = acc[n][3] + bs + L[(size_t)(p * 16 + lg * 4 + 3) * 128 + o];
            int wo0 = p * 16 + lg * 4;
            *(float4*)(out + (size_t)(b * OO + o) * HWs + ho * WW + wo0) = v;
        }
    }
}

extern "C" void kernel_launch(void* const* d_in, const int* in_sizes, int n_in,
                              void* d_out, int out_size, void* d_ws, size_t ws_size,
                              hipStream_t stream) {
    const float* inp    = (const float*)d_in[0];
    const float* offset = (const float*)d_in[1];
    const float* mask   = (const float*)d_in[2];
    const float* weight = (const float*)d_in[3];
    const float* bias   = (const float*)d_in[4];
    float* out = (float*)d_out;

    _Float16* inh = (_Float16*)d_ws;  // 8 MB
    unsigned short* wbf =
        (unsigned short*)((char*)d_ws + (size_t)BB * HWs * CC * sizeof(_Float16));

    prep_input<<<dim3(128, 8), 256, 0, stream>>>(inp, inh);
    prep_weight<<<dim3((KT * OO * CC + 255) / 256), 256, 0, stream>>>(weight, wbf);
    deform_main<<<dim3(512), 512, 0, stream>>>(inh, wbf, offset, mask, bias, out);
}

// Round 11
// 173.709 us; speedup vs baseline: 1.5055x; 1.5055x over previous
//
#include <hip/hip_runtime.h>

#define BB 8
#define CC 128
#define HH 64
#define WW 64
#define OO 128
#define KT 9
#define HWs (HH * WW)

typedef __attribute__((ext_vector_type(8))) _Float16 half8;
typedef __attribute__((ext_vector_type(8))) short short8;
typedef __attribute__((ext_vector_type(4))) float f32x4;

__device__ inline unsigned short f2bf(float f) {
    union { float f; unsigned int u; } x; x.f = f;
    unsigned int u = x.u;
    unsigned int r = u + 0x7fff + ((u >> 16) & 1);
    return (unsigned short)(r >> 16);
}

// ---- prep 1: NCHW f32 -> NHWC f16 (proven) ----
__global__ __launch_bounds__(256) void prep_input(
    const float* __restrict__ in, _Float16* __restrict__ out) {
    __shared__ float t[CC][33];
    int b = blockIdx.y;
    int s0 = blockIdx.x * 32;
    int s = threadIdx.x & 31;
    int c0 = threadIdx.x >> 5;
    const float* ip = in + (size_t)b * CC * HWs;
#pragma unroll
    for (int c = 0; c < CC; c += 8)
        t[c + c0][s] = ip[(size_t)(c + c0) * HWs + s0 + s];
    __syncthreads();
    int ws = threadIdx.x >> 3;
    int cg = (threadIdx.x & 7) * 16;
    _Float16 v[16];
#pragma unroll
    for (int i = 0; i < 16; ++i) v[i] = (_Float16)t[cg + i][ws];
    _Float16* op = out + ((size_t)(b * HWs) + s0 + ws) * CC + cg;
    *(half8*)op = *(half8*)&v[0];
    *(half8*)(op + 8) = *(half8*)&v[8];
}

// ---- prep 2 (proven): weight (O,C,3,3) f32 -> wbf[k][o][c] bf16 ----
__global__ __launch_bounds__(256) void prep_weight(
    const float* __restrict__ w, unsigned short* __restrict__ wbf) {
    int i = blockIdx.x * 256 + threadIdx.x;
    if (i >= KT * OO * CC) return;
    int k = i / (OO * CC);
    int r = i % (OO * CC);
    int o = r >> 7, c = r & 127;
    wbf[i] = f2bf(w[o * (CC * KT) + c * KT + k]);
}

// ---- main ----
struct GatherR {
    half8 g[8];                 // [corner][cc]: 4 corners x 2 chunks of 8 ch
    float w00, w01, w10, w11;
};

__device__ __forceinline__ void sample_issue(
    const _Float16* __restrict__ base, int ho, int wo, int cs, int k,
    float oy, float ox, float mm, GatherR& G) {
    int kh = k / 3, kw = k % 3;
    float py = (float)(ho - 1 + kh) + oy;
    float px = (float)(wo - 1 + kw) + ox;
    float fy = floorf(py), fx = floorf(px);
    float wy1 = py - fy, wx1 = px - fx;
    float wy0 = 1.f - wy1, wx0 = 1.f - wx1;
    int y0 = (int)fy, x0 = (int)fx;
    int y1 = y0 + 1, x1 = x0 + 1;
    bool vy0 = (y0 >= 0) & (y0 < HH);
    bool vy1 = (y1 >= 0) & (y1 < HH);
    bool vx0 = (x0 >= 0) & (x0 < WW);
    bool vx1 = (x1 >= 0) & (x1 < WW);
    G.w00 = (vy0 & vx0) ? wy0 * wx0 * mm : 0.f;
    G.w01 = (vy0 & vx1) ? wy0 * wx1 * mm : 0.f;
    G.w10 = (vy1 & vx0) ? wy1 * wx0 * mm : 0.f;
    G.w11 = (vy1 & vx1) ? wy1 * wx1 * mm : 0.f;
    int y0c = min(max(y0, 0), HH - 1), y1c = min(max(y1, 0), HH - 1);
    int x0c = min(max(x0, 0), WW - 1), x1c = min(max(x1, 0), WW - 1);
    const _Float16* p00 = base + (size_t)(y0c * WW + x0c) * CC + cs;
    const _Float16* p01 = base + (size_t)(y0c * WW + x1c) * CC + cs;
    const _Float16* p10 = base + (size_t)(y1c * WW + x0c) * CC + cs;
    const _Float16* p11 = base + (size_t)(y1c * WW + x1c) * CC + cs;
    G.g[0] = *(const half8*)p00;  G.g[1] = *(const half8*)(p00 + 32);
    G.g[2] = *(const half8*)p01;  G.g[3] = *(const half8*)(p01 + 32);
    G.g[4] = *(const half8*)p10;  G.g[5] = *(const half8*)(p10 + 32);
    G.g[6] = *(const half8*)p11;  G.g[7] = *(const half8*)(p11 + 32);
}

__global__ __launch_bounds__(256, 4) void deform_main(
    const _Float16* __restrict__ inh, const unsigned short* __restrict__ wbf,
    const float* __restrict__ offset, const float* __restrict__ mask,
    const float* __restrict__ bias, float* __restrict__ out) {
    // 32 KB single-buffer B; reused as f32 reduction buffer at the end
    __shared__ unsigned short Bl[OO * CC];

    // 1024 blocks; XCD x owns image b=x; consecutive-on-XCD = consecutive rows
    int hw = blockIdx.x;
    int lb = (hw & 7) * 128 + (hw >> 3);
    int b = lb >> 7;
    int rem = lb & 127;
    int ho = rem >> 1;
    int px0 = (rem & 1) * 32;

    int tid = threadIdx.x;
    int wv = tid >> 6, l = tid & 63;
    int lr = l & 15, lg = l >> 4;
    int p = wv >> 1;               // pixel half (0..1)
    int khalf = wv & 1;            // channel half (0..1)
    int wo = px0 + p * 16 + lr;    // this lane's pixel
    int cs = khalf * 64 + lg * 8;  // first channel chunk (second is +32)

    // B staging role: each thread 128 B of one row (8 x int4)
    int o_s = tid >> 1;
    int cb0 = (tid & 1) * 128;

    const _Float16* base = inh + (size_t)b * HWs * CC;
    const float* offp = offset + (size_t)b * 18 * HWs + ho * WW + wo;
    const float* mskp = mask + (size_t)b * 9 * HWs + ho * WW + wo;

    f32x4 acc[8] = {};
    GatherR G;
    int4 breg[8];

    // ---- prologue: issue B(0) (oldest vmem), gathers(0), offs(1) ----
    {
        const int4* src = (const int4*)((const char*)wbf + (size_t)o_s * 256 + cb0);
#pragma unroll
        for (int j = 0; j < 8; ++j) breg[j] = src[j];
        float oy = offp[0], ox = offp[HWs], mm = mskp[0];
        sample_issue(base, ho, wo, cs, 0, oy, ox, mm, G);
    }
    float oyN = offp[2 * HWs], oxN = offp[3 * HWs], mmN = mskp[HWs];

    for (int k = 0; k < KT; ++k) {
        // bar A: all waves done reading Bl (previous tap)
        __syncthreads();
        // write B(k): waits only the B(k) loads (oldest; gathers stay in flight)
        {
            char* dst = (char*)Bl + o_s * 256;
#pragma unroll
            for (int j = 0; j < 8; ++j)
                *(int4*)(dst + ((cb0 + j * 16) ^ ((o_s & 15) << 4))) = breg[j];
        }
        // bar B: B(k) visible
        __syncthreads();

        // issue B(k+1) loads (older than gathers(k+1) in the vmem queue)
        if (k < KT - 1) {
            const int4* src = (const int4*)((const char*)wbf +
                              (size_t)(k + 1) * OO * CC * 2 + (size_t)o_s * 256 + cb0);
#pragma unroll
            for (int j = 0; j < 8; ++j) breg[j] = src[j];
        }

        // interp tap k (consumes gathers(k), issued one full tap ago)
        short8 af[2];
#pragma unroll
        for (int cc = 0; cc < 2; ++cc)
#pragma unroll
            for (int j = 0; j < 8; ++j) {
                float s = G.w00 * (float)G.g[0 * 2 + cc][j] +
                          G.w01 * (float)G.g[1 * 2 + cc][j] +
                          G.w10 * (float)G.g[2 * 2 + cc][j] +
                          G.w11 * (float)G.g[3 * 2 + cc][j];
                af[cc][j] = (short)f2bf(s);
            }

        // issue gathers(k+1); prefetch offsets(k+2)
        if (k < KT - 1) {
            sample_issue(base, ho, wo, cs, k + 1, oyN, oxN, mmN, G);
            if (k < KT - 2) {
                oyN = offp[(2 * k + 4) * HWs];
                oxN = offp[(2 * k + 5) * HWs];
                mmN = mskp[(k + 2) * HWs];
            }
        }

        // MFMA tap k: A regs, B from Bl (r8-proven swizzle)
#pragma unroll
        for (int cc = 0; cc < 2; ++cc) {
            unsigned colb = (unsigned)((khalf * 2 + cc) * 64 + lg * 16);
#pragma unroll
            for (int n = 0; n < 8; ++n) {
                int o = n * 16 + lr;
                unsigned baddr = (unsigned)(o * 256 + (colb ^ (lr << 4)));
                short8 bf = *(const short8*)((const char*)Bl + baddr);
                acc[n] = __builtin_amdgcn_mfma_f32_16x16x32_bf16(
                    af[cc], bf, acc[n], 0, 0, 0);
            }
        }
    }

    // ---- K-split pair reduction reusing Bl as f32 buffer (16 KB) ----
    __syncthreads();
    float* L = (float*)Bl;  // 32 px x 128 o
    if (khalf) {
#pragma unroll
        for (int n = 0; n < 8; ++n)
#pragma unroll
            for (int j = 0; j < 4; ++j)
                L[(size_t)(p * 16 + lg * 4 + j) * 128 + n * 16 + lr] = acc[n][j];
    }
    __syncthreads();
    if (!khalf) {
#pragma unroll
        for (int n = 0; n < 8; ++n) {
            int o = n * 16 + lr;
            float bs = bias[o];
            float4 v;
            v.x = acc[n][0] + bs + L[(size_t)(p * 16 + lg * 4 + 0) * 128 + o];
            v.y = acc[n][1] + bs + L[(size_t)(p * 16 + lg * 4 + 1) * 128 + o];
            v.z = acc[n][2] + bs + L[(size_t)(p * 16 + lg * 4 + 2) * 128 + o];
            v.w = acc[n][3] + bs + L[(size_t)(p * 16 + lg * 4 + 3) * 128 + o];
            int wo0 = px0 + p * 16 + lg * 4;
            *(float4*)(out + (size_t)(b * OO + o) * HWs + ho * WW + wo0) = v;
        }
    }
}

extern "C" void kernel_launch(void* const* d_in, const int* in_sizes, int n_in,
                              void* d_out, int out_size, void* d_ws, size_t ws_size,
                              hipStream_t stream) {
    const float* inp    = (const float*)d_in[0];
    const float* offset = (const float*)d_in[1];
    const float* mask   = (const float*)d_in[2];
    const float* weight = (const float*)d_in[3];
    const float* bias   = (const float*)d_in[4];
    float* out = (float*)d_out;

    _Float16* inh = (_Float16*)d_ws;  // 8 MB
    unsigned short* wbf =
        (unsigned short*)((char*)d_ws + (size_t)BB * HWs * CC * sizeof(_Float16));

    prep_input<<<dim3(128, 8), 256, 0, stream>>>(inp, inh);
    prep_weight<<<dim3((KT * OO * CC + 255) / 256), 256, 0, stream>>>(weight, wbf);
    deform_main<<<dim3(1024), 256, 0, stream>>>(inh, wbf, offset, mask, bias, out);
}

// Round 12
// 63.705 us; speedup vs baseline: 4.1051x; 2.7268x over previous
//
#include <hip/hip_runtime.h>

#define BB 8
#define CC 128
#define HH 64
#define WW 64
#define OO 128
#define KT 9
#define HWs (HH * WW)

typedef __attribute__((ext_vector_type(8))) _Float16 half8;
typedef __attribute__((ext_vector_type(8))) short short8;
typedef __attribute__((ext_vector_type(4))) float f32x4;

__device__ inline unsigned short f2bf(float f) {
    union { float f; unsigned int u; } x; x.f = f;
    unsigned int u = x.u;
    unsigned int r = u + 0x7fff + ((u >> 16) & 1);
    return (unsigned short)(r >> 16);
}

__device__ __forceinline__ void gload_lds16(const void* g, void* l) {
    __builtin_amdgcn_global_load_lds(
        (__attribute__((address_space(1))) void*)g,
        (__attribute__((address_space(3))) void*)l, 16, 0, 0);
}

// ---- prep 1: NCHW f32 -> NHWC f16 (proven) ----
__global__ __launch_bounds__(256) void prep_input(
    const float* __restrict__ in, _Float16* __restrict__ out) {
    __shared__ float t[CC][33];
    int b = blockIdx.y;
    int s0 = blockIdx.x * 32;
    int s = threadIdx.x & 31;
    int c0 = threadIdx.x >> 5;
    const float* ip = in + (size_t)b * CC * HWs;
#pragma unroll
    for (int c = 0; c < CC; c += 8)
        t[c + c0][s] = ip[(size_t)(c + c0) * HWs + s0 + s];
    __syncthreads();
    int ws = threadIdx.x >> 3;
    int cg = (threadIdx.x & 7) * 16;
    _Float16 v[16];
#pragma unroll
    for (int i = 0; i < 16; ++i) v[i] = (_Float16)t[cg + i][ws];
    _Float16* op = out + ((size_t)(b * HWs) + s0 + ws) * CC + cg;
    *(half8*)op = *(half8*)&v[0];
    *(half8*)(op + 8) = *(half8*)&v[8];
}

// ---- prep 2: weight (O,C,3,3) f32 -> PRE-SWIZZLED wbf[k] (32 KB/tap) ----
// element (k,o,c) stored at byte k*32768 + o*256 + ((2c) ^ ((o&15)<<4)).
// Linear LDS copy then swizzled b128 reads == r8-proven conflict-free layout.
__global__ __launch_bounds__(256) void prep_weight(
    const float* __restrict__ w, unsigned short* __restrict__ wbf) {
    int i = blockIdx.x * 256 + threadIdx.x;
    if (i >= KT * OO * CC) return;
    int k = i / (OO * CC);
    int r = i % (OO * CC);
    int o = r >> 7, c = r & 127;
    unsigned byte = (unsigned)(o * 256 + ((2 * c) ^ ((o & 15) << 4)));
    *(unsigned short*)((char*)wbf + (size_t)k * 32768 + byte) =
        f2bf(w[o * (CC * KT) + c * KT + k]);
}

// ---- main ----
struct GatherR {
    half8 g[8];                 // [corner][cc]: 4 corners x 2 chunks of 8 ch
    float w00, w01, w10, w11;
};

__device__ __forceinline__ void sample_issue(
    const _Float16* __restrict__ base, int ho, int wo, int cs, int k,
    float oy, float ox, float mm, GatherR& G) {
    int kh = k / 3, kw = k % 3;
    float py = (float)(ho - 1 + kh) + oy;
    float px = (float)(wo - 1 + kw) + ox;
    float fy = floorf(py), fx = floorf(px);
    float wy1 = py - fy, wx1 = px - fx;
    float wy0 = 1.f - wy1, wx0 = 1.f - wx1;
    int y0 = (int)fy, x0 = (int)fx;
    int y1 = y0 + 1, x1 = x0 + 1;
    bool vy0 = (y0 >= 0) & (y0 < HH);
    bool vy1 = (y1 >= 0) & (y1 < HH);
    bool vx0 = (x0 >= 0) & (x0 < WW);
    bool vx1 = (x1 >= 0) & (x1 < WW);
    G.w00 = (vy0 & vx0) ? wy0 * wx0 * mm : 0.f;
    G.w01 = (vy0 & vx1) ? wy0 * wx1 * mm : 0.f;
    G.w10 = (vy1 & vx0) ? wy1 * wx0 * mm : 0.f;
    G.w11 = (vy1 & vx1) ? wy1 * wx1 * mm : 0.f;
    int y0c = min(max(y0, 0), HH - 1), y1c = min(max(y1, 0), HH - 1);
    int x0c = min(max(x0, 0), WW - 1), x1c = min(max(x1, 0), WW - 1);
    const _Float16* p00 = base + (size_t)(y0c * WW + x0c) * CC + cs;
    const _Float16* p01 = base + (size_t)(y0c * WW + x1c) * CC + cs;
    const _Float16* p10 = base + (size_t)(y1c * WW + x0c) * CC + cs;
    const _Float16* p11 = base + (size_t)(y1c * WW + x1c) * CC + cs;
    G.g[0] = *(const half8*)p00;  G.g[1] = *(const half8*)(p00 + 32);
    G.g[2] = *(const half8*)p01;  G.g[3] = *(const half8*)(p01 + 32);
    G.g[4] = *(const half8*)p10;  G.g[5] = *(const half8*)(p10 + 32);
    G.g[6] = *(const half8*)p11;  G.g[7] = *(const half8*)(p11 + 32);
}

__global__ __launch_bounds__(256, 2) void deform_main(
    const _Float16* __restrict__ inh, const unsigned short* __restrict__ wbf,
    const float* __restrict__ offset, const float* __restrict__ mask,
    const float* __restrict__ bias, float* __restrict__ out) {
    // 32 KB single-buffer B (pre-swizzled); reused as f32 reduction buffer
    __shared__ unsigned short Bl[OO * CC];

    // 1024 blocks; XCD x owns image b=x
    int hw = blockIdx.x;
    int lb = (hw & 7) * 128 + (hw >> 3);
    int b = lb >> 7;
    int rem = lb & 127;
    int ho = rem >> 1;
    int px0 = (rem & 1) * 32;

    int tid = threadIdx.x;
    int wv = tid >> 6, l = tid & 63;
    int lr = l & 15, lg = l >> 4;
    int p = wv >> 1;               // pixel half (0..1)
    int khalf = wv & 1;            // channel half (0..1)
    int wo = px0 + p * 16 + lr;    // this lane's pixel
    int cs = khalf * 64 + lg * 8;  // first channel chunk (second is +32)

    const _Float16* base = inh + (size_t)b * HWs * CC;
    const float* offp = offset + (size_t)b * 18 * HWs + ho * WW + wo;
    const float* mskp = mask + (size_t)b * 9 * HWs + ho * WW + wo;

    // staging: per wave 8 KB, lane-linear (HW: uniform LDS base + lane*16)
    const char* wsrc = (const char*)wbf + (size_t)wv * 8192 + (size_t)l * 16;
    char* ldst = (char*)Bl + wv * 8192;

    f32x4 acc[8] = {};
    GatherR G;

    // ---- prologue: gathers(0); offsets(1) prefetch ----
    {
        float oy = offp[0], ox = offp[HWs], mm = mskp[0];
        sample_issue(base, ho, wo, cs, 0, oy, ox, mm, G);
    }
    float oyN = offp[2 * HWs], oxN = offp[3 * HWs], mmN = mskp[HWs];

    for (int k = 0; k < KT; ++k) {
        // (1) interp tap k — consumes gathers(k); after this, no vmem in flight
        short8 af[2];
#pragma unroll
        for (int cc = 0; cc < 2; ++cc)
#pragma unroll
            for (int j = 0; j < 8; ++j) {
                float s = G.w00 * (float)G.g[0 * 2 + cc][j] +
                          G.w01 * (float)G.g[1 * 2 + cc][j] +
                          G.w10 * (float)G.g[2 * 2 + cc][j] +
                          G.w11 * (float)G.g[3 * 2 + cc][j];
                af[cc][j] = (short)f2bf(s);
            }

        // (2) bar A: all waves done reading Bl (tap k-1 MFMA)
        __syncthreads();

        // (3) stage B(k): 8 x 1 KB lds-direct per wave, zero VGPRs
        {
            const char* s = wsrc + (size_t)k * 32768;
#pragma unroll
            for (int j = 0; j < 8; ++j)
                gload_lds16(s + j * 1024, ldst + j * 1024);
        }
        // (4) bar B: compiler's vmcnt(0) drains staging only
        __syncthreads();

        // (5) issue gathers(k+1) (covered by MFMA(k) + next interp distance)
        if (k < KT - 1) {
            sample_issue(base, ho, wo, cs, k + 1, oyN, oxN, mmN, G);
            if (k < KT - 2) {
                oyN = offp[(2 * k + 4) * HWs];
                oxN = offp[(2 * k + 5) * HWs];
                mmN = mskp[(k + 2) * HWs];
            }
        }

        // (6) MFMA tap k: A regs, B from Bl (r8-proven swizzled reads)
#pragma unroll
        for (int cc = 0; cc < 2; ++cc) {
            unsigned colb = (unsigned)((khalf * 2 + cc) * 64 + lg * 16);
#pragma unroll
            for (int n = 0; n < 8; ++n) {
                int o = n * 16 + lr;
                unsigned baddr = (unsigned)(o * 256 + (colb ^ (lr << 4)));
                short8 bf = *(const short8*)((const char*)Bl + baddr);
                acc[n] = __builtin_amdgcn_mfma_f32_16x16x32_bf16(
                    af[cc], bf, acc[n], 0, 0, 0);
            }
        }
    }

    // ---- K-split pair reduction reusing Bl as f32 buffer (16 KB) ----
    __syncthreads();
    float* L = (float*)Bl;  // 32 px x 128 o
    if (khalf) {
#pragma unroll
        for (int n = 0; n < 8; ++n)
#pragma unroll
            for (int j = 0; j < 4; ++j)
                L[(size_t)(p * 16 + lg * 4 + j) * 128 + n * 16 + lr] = acc[n][j];
    }
    __syncthreads();
    if (!khalf) {
#pragma unroll
        for (int n = 0; n < 8; ++n) {
            int o = n * 16 + lr;
            float bs = bias[o];
            float4 v;
            v.x = acc[n][0] + bs + L[(size_t)(p * 16 + lg * 4 + 0) * 128 + o];
            v.y = acc[n][1] + bs + L[(size_t)(p * 16 + lg * 4 + 1) * 128 + o];
            v.z = acc[n][2] + bs + L[(size_t)(p * 16 + lg * 4 + 2) * 128 + o];
            v.w = acc[n][3] + bs + L[(size_t)(p * 16 + lg * 4 + 3) * 128 + o];
            int wo0 = px0 + p * 16 + lg * 4;
            *(float4*)(out + (size_t)(b * OO + o) * HWs + ho * WW + wo0) = v;
        }
    }
}

extern "C" void kernel_launch(void* const* d_in, const int* in_sizes, int n_in,
                              void* d_out, int out_size, void* d_ws, size_t ws_size,
                              hipStream_t stream) {
    const float* inp    = (const float*)d_in[0];
    const float* offset = (const float*)d_in[1];
    const float* mask   = (const float*)d_in[2];
    const float* weight = (const float*)d_in[3];
    const float* bias   = (const float*)d_in[4];
    float* out = (float*)d_out;

    _Float16* inh = (_Float16*)d_ws;  // 8 MB
    unsigned short* wbf =
        (unsigned short*)((char*)d_ws + (size_t)BB * HWs * CC * sizeof(_Float16));

    prep_input<<<dim3(128, 8), 256, 0, stream>>>(inp, inh);
    prep_weight<<<dim3((KT * OO * CC + 255) / 256), 256, 0, stream>>>(weight, wbf);
    deform_main<<<dim3(1024), 256, 0, stream>>>(inh, wbf, offset, mask, bias, out);
}

// Round 13
// 53.845 us; speedup vs baseline: 4.8569x; 1.1831x over previous
//
#include <hip/hip_runtime.h>

#define BB 8
#define CC 128
#define HH 64
#define WW 64
#define OO 128
#define KT 9
#define HWs (HH * WW)

typedef __attribute__((ext_vector_type(8))) _Float16 half8;
typedef __attribute__((ext_vector_type(8))) short short8;
typedef __attribute__((ext_vector_type(8))) unsigned short ushort8;
typedef __attribute__((ext_vector_type(4))) float f32x4;

__device__ inline unsigned short f2bf(float f) {
    union { float f; unsigned int u; } x; x.f = f;
    unsigned int u = x.u;
    unsigned int r = u + 0x7fff + ((u >> 16) & 1);
    return (unsigned short)(r >> 16);
}

__device__ __forceinline__ void gload_lds16(const void* g, void* l) {
    __builtin_amdgcn_global_load_lds(
        (__attribute__((address_space(1))) void*)g,
        (__attribute__((address_space(3))) void*)l, 16, 0, 0);
}

// ---- prep 1: NCHW f32 -> NHWC f16 (proven) ----
__global__ __launch_bounds__(256) void prep_input(
    const float* __restrict__ in, _Float16* __restrict__ out) {
    __shared__ float t[CC][33];
    int b = blockIdx.y;
    int s0 = blockIdx.x * 32;
    int s = threadIdx.x & 31;
    int c0 = threadIdx.x >> 5;
    const float* ip = in + (size_t)b * CC * HWs;
#pragma unroll
    for (int c = 0; c < CC; c += 8)
        t[c + c0][s] = ip[(size_t)(c + c0) * HWs + s0 + s];
    __syncthreads();
    int ws = threadIdx.x >> 3;
    int cg = (threadIdx.x & 7) * 16;
    _Float16 v[16];
#pragma unroll
    for (int i = 0; i < 16; ++i) v[i] = (_Float16)t[cg + i][ws];
    _Float16* op = out + ((size_t)(b * HWs) + s0 + ws) * CC + cg;
    *(half8*)op = *(half8*)&v[0];
    *(half8*)(op + 8) = *(half8*)&v[8];
}

// ---- prep 2 (r12-proven): weight -> PRE-SWIZZLED wbf[k] (32 KB/tap) ----
// element (k,o,c) at byte k*32768 + o*256 + ((2c) ^ ((o&15)<<4))
__global__ __launch_bounds__(256) void prep_weight(
    const float* __restrict__ w, unsigned short* __restrict__ wbf) {
    int i = blockIdx.x * 256 + threadIdx.x;
    if (i >= KT * OO * CC) return;
    int k = i / (OO * CC);
    int r = i % (OO * CC);
    int o = r >> 7, c = r & 127;
    unsigned byte = (unsigned)(o * 256 + ((2 * c) ^ ((o & 15) << 4)));
    *(unsigned short*)((char*)wbf + (size_t)k * 32768 + byte) =
        f2bf(w[o * (CC * KT) + c * KT + k]);
}

// ---- kernel S: sampler. thread = (px, 16ch, tap). no barriers/LDS. ----
// As row = px within chunk, 2304 B/row; K index = tap*128 + c;
// byte col pre-swizzled: (2c) ^ ((px&15)<<4)  [rule #21: src-perm == read-perm]
__global__ __launch_bounds__(256, 2) void deform_sample(
    const _Float16* __restrict__ inh, const float* __restrict__ offset,
    const float* __restrict__ mask, unsigned short* __restrict__ As,
    int b0, int lnb) {
    int nb = 1 << lnb;
    int hw = blockIdx.x;
    int xcd = hw & 7;
    int j = hw >> 3;                         // [0, nb*144)
    int bl = xcd & (nb - 1);                 // local image
    int task = (xcd >> lnb) * (144 << lnb) + j;  // [0,1152)
    int tap = task >> 7;
    int blk = task & 127;
    int tid = threadIdx.x;
    int px = blk * 32 + (tid >> 3);          // [0,4096)
    int cg = (tid & 7) * 16;                 // channel start
    int ho = px >> 6, wo = px & 63;
    int b = b0 + bl;

    const _Float16* base = inh + (size_t)b * HWs * CC;
    float oy = offset[(size_t)(b * 18 + 2 * tap) * HWs + ho * WW + wo];
    float ox = offset[(size_t)(b * 18 + 2 * tap + 1) * HWs + ho * WW + wo];
    float mm = mask[(size_t)(b * 9 + tap) * HWs + ho * WW + wo];

    int kh = tap / 3, kw = tap % 3;
    float py = (float)(ho - 1 + kh) + oy;
    float pxf = (float)(wo - 1 + kw) + ox;
    float fy = floorf(py), fx = floorf(pxf);
    float wy1 = py - fy, wx1 = pxf - fx;
    float wy0 = 1.f - wy1, wx0 = 1.f - wx1;
    int y0 = (int)fy, x0 = (int)fx;
    int y1 = y0 + 1, x1 = x0 + 1;
    bool vy0 = (y0 >= 0) & (y0 < HH);
    bool vy1 = (y1 >= 0) & (y1 < HH);
    bool vx0 = (x0 >= 0) & (x0 < WW);
    bool vx1 = (x1 >= 0) & (x1 < WW);
    float w00 = (vy0 & vx0) ? wy0 * wx0 * mm : 0.f;
    float w01 = (vy0 & vx1) ? wy0 * wx1 * mm : 0.f;
    float w10 = (vy1 & vx0) ? wy1 * wx0 * mm : 0.f;
    float w11 = (vy1 & vx1) ? wy1 * wx1 * mm : 0.f;
    int y0c = min(max(y0, 0), HH - 1), y1c = min(max(y1, 0), HH - 1);
    int x0c = min(max(x0, 0), WW - 1), x1c = min(max(x1, 0), WW - 1);
    const _Float16* p00 = base + (size_t)(y0c * WW + x0c) * CC + cg;
    const _Float16* p01 = base + (size_t)(y0c * WW + x1c) * CC + cg;
    const _Float16* p10 = base + (size_t)(y1c * WW + x0c) * CC + cg;
    const _Float16* p11 = base + (size_t)(y1c * WW + x1c) * CC + cg;
    half8 g00a = *(const half8*)p00, g00b = *(const half8*)(p00 + 8);
    half8 g01a = *(const half8*)p01, g01b = *(const half8*)(p01 + 8);
    half8 g10a = *(const half8*)p10, g10b = *(const half8*)(p10 + 8);
    half8 g11a = *(const half8*)p11, g11b = *(const half8*)(p11 + 8);

    ushort8 o0, o1;
#pragma unroll
    for (int q = 0; q < 8; ++q) {
        float s = w00 * (float)g00a[q] + w01 * (float)g01a[q] +
                  w10 * (float)g10a[q] + w11 * (float)g11a[q];
        o0[q] = f2bf(s);
    }
#pragma unroll
    for (int q = 0; q < 8; ++q) {
        float s = w00 * (float)g00b[q] + w01 * (float)g01b[q] +
                  w10 * (float)g10b[q] + w11 * (float)g11b[q];
        o1[q] = f2bf(s);
    }
    char* rowp = (char*)As + ((size_t)bl * 4096 + px) * 2304 + tap * 256;
    unsigned sw = (unsigned)((px & 15) << 4);
    *(ushort8*)(rowp + ((2 * cg) ^ sw)) = o0;
    *(ushort8*)(rowp + ((2 * cg + 16) ^ sw)) = o1;
}

// ---- kernel G: GEMM  M=nb*4096 px, N=128 O, K=1152 (9 taps x 128 ch) ----
// block = 256 thr / 4 waves; tile 64 px x 128 O; wave = 16 px x 128 O.
__global__ __launch_bounds__(256, 2) void deform_gemm(
    const unsigned short* __restrict__ As, const unsigned short* __restrict__ wbf,
    const float* __restrict__ bias, float* __restrict__ out, int b0) {
    __shared__ unsigned short Al[64 * 128];   // 16 KB, rows pre-swizzled
    __shared__ unsigned short Bl[OO * CC];    // 32 KB, rows pre-swizzled

    int bpx = blockIdx.x * 64;                // px base within chunk
    int tid = threadIdx.x;
    int wv = tid >> 6, l = tid & 63;
    int lr = l & 15, lg = l >> 4;

    const char* bwsrc = (const char*)wbf + (size_t)wv * 8192 + (size_t)l * 16;
    char* bldst = (char*)Bl + wv * 8192;

    f32x4 acc[8] = {};

    for (int k = 0; k < KT; ++k) {
        __syncthreads();   // bar A: previous tap's LDS reads complete
        // stage B(k): 8 KB per wave, zero-VGPR lds-direct
        {
            const char* s = bwsrc + (size_t)k * 32768;
#pragma unroll
            for (int j2 = 0; j2 < 8; ++j2)
                gload_lds16(s + j2 * 1024, bldst + j2 * 1024);
        }
        // stage A(k): 4 KB per wave (rows wv*16..wv*16+15), lane-linear dest
        {
#pragma unroll
            for (int j2 = 0; j2 < 4; ++j2) {
                int row = wv * 16 + j2 * 4 + lg;
                const char* s = (const char*)As +
                    (size_t)(bpx + row) * 2304 + (size_t)k * 256 + lr * 16;
                gload_lds16(s, (char*)Al + (wv * 16 + j2 * 4) * 256);
            }
        }
        __syncthreads();   // bar B: staging drained (compiler vmcnt(0))

        // MFMA: 4 K-steps x 8 N-frags
#pragma unroll
        for (int c32 = 0; c32 < 4; ++c32) {
            int arow = wv * 16 + lr;
            unsigned ab = (unsigned)(arow * 256 + ((c32 * 64 + lg * 16) ^ (lr << 4)));
            short8 af = *(const short8*)((const char*)Al + ab);
#pragma unroll
            for (int n = 0; n < 8; ++n) {
                int o = n * 16 + lr;
                unsigned bb = (unsigned)(o * 256 + ((c32 * 64 + lg * 16) ^ (lr << 4)));
                short8 bf = *(const short8*)((const char*)Bl + bb);
                acc[n] = __builtin_amdgcn_mfma_f32_16x16x32_bf16(
                    af, bf, acc[n], 0, 0, 0);
            }
        }
    }

    // epilogue: row px = bpx + wv*16 + lg*4 + j ; col o = n*16 + lr
    int sp0 = bpx + wv * 16 + lg * 4;
    int b = b0 + (sp0 >> 12);
    int sp = sp0 & 4095;
    int ho = sp >> 6;
    int wo0 = sp & 63;
#pragma unroll
    for (int n = 0; n < 8; ++n) {
        int o = n * 16 + lr;
        float bs = bias[o];
        float4 v;
        v.x = acc[n][0] + bs;
        v.y = acc[n][1] + bs;
        v.z = acc[n][2] + bs;
        v.w = acc[n][3] + bs;
        *(float4*)(out + (size_t)(b * OO + o) * HWs + ho * WW + wo0) = v;
    }
}

extern "C" void kernel_launch(void* const* d_in, const int* in_sizes, int n_in,
                              void* d_out, int out_size, void* d_ws, size_t ws_size,
                              hipStream_t stream) {
    const float* inp    = (const float*)d_in[0];
    const float* offset = (const float*)d_in[1];
    const float* mask   = (const float*)d_in[2];
    const float* weight = (const float*)d_in[3];
    const float* bias   = (const float*)d_in[4];
    float* out = (float*)d_out;

    const size_t inh_b = (size_t)BB * HWs * CC * sizeof(_Float16);  // 8 MB
    const size_t wbf_b = (size_t)KT * OO * CC * sizeof(unsigned short);
    _Float16* inh = (_Float16*)d_ws;
    unsigned short* wbf = (unsigned short*)((char*)d_ws + inh_b);
    unsigned short* As = (unsigned short*)((char*)d_ws + inh_b + wbf_b);

    // chunk size: nb images per sampler+GEMM pass (As = nb * 9 MiB)
    size_t avail = (ws_size > inh_b + wbf_b) ? ws_size - inh_b - wbf_b : 0;
    int lnb = 3;
    while (lnb > 0 && ((size_t)(1 << lnb)) * 4096u * 2304u > avail) --lnb;
    int nb = 1 << lnb;

    prep_input<<<dim3(128, 8), 256, 0, stream>>>(inp, inh);
    prep_weight<<<dim3((KT * OO * CC + 255) / 256), 256, 0, stream>>>(weight, wbf);
    for (int b0 = 0; b0 < BB; b0 += nb) {
        deform_sample<<<dim3(nb * 1152), 256, 0, stream>>>(
            inh, offset, mask, As, b0, lnb);
        deform_gemm<<<dim3(nb * 64), 256, 0, stream>>>(As, wbf, bias, out, b0);
    }
}